// Round 1
// 3027.623 us; speedup vs baseline: 2.2648x; 2.2648x over previous
//
#include <hip/hip_runtime.h>

typedef __attribute__((ext_vector_type(8))) short short8;
typedef __attribute__((ext_vector_type(4))) float f32x4;

#define B_   64
#define S_   512
#define V_   1400
#define VP_  1408
#define H_   256
#define G4_  1024
#define NC_  128
#define CH_  64    // time-chunk length (8 chunks of 64 steps)

__device__ __forceinline__ unsigned short f2bf(float f) {
    unsigned u = __builtin_bit_cast(unsigned, f);
    u += 0x7FFFu + ((u >> 16) & 1u);
    return (unsigned short)(u >> 16);
}
__device__ __forceinline__ float bf2f(unsigned short h) {
    unsigned u = ((unsigned)h) << 16;
    return __builtin_bit_cast(float, u);
}
__device__ __forceinline__ float fsig(float x) {
    x = fminf(fmaxf(x, -40.f), 40.f);
    float e = __builtin_amdgcn_exp2f(x * -1.44269504f);
    return __builtin_amdgcn_rcpf(1.0f + e);
}
__device__ __forceinline__ float ftanh(float x) {
    x = fminf(fmaxf(x, -40.f), 40.f);
    float e = __builtin_amdgcn_exp2f(x * 2.88539008f);
    return 1.0f - 2.0f * __builtin_amdgcn_rcpf(e + 1.0f);
}

// device-scope (coherent-point) 16B load: bypasses non-coherent L1/L2 so
// cross-XCD peer data is seen without cache invalidates.
__device__ __forceinline__ short8 gload16_sc1(const unsigned short* p) {
    short8 r;
    asm volatile("global_load_dwordx4 %0, %1, off sc1"
                 : "=v"(r) : "v"((unsigned long long)p));
    return r;
}
// device-scope write-through 2B store (peer-visible after vmcnt drain).
__device__ __forceinline__ void gstore_short_sc1(unsigned short* p, unsigned v) {
    asm volatile("global_store_short %0, %1, off sc1"
                 :: "v"((unsigned long long)p), "v"(v) : "memory");
}

// ---------------------------------------------------------------- K0: prep
__global__ void k0_prep(const float* __restrict__ emb,
                        const float* __restrict__ Wa1, const float* __restrict__ Wa2,
                        const float* __restrict__ Wd1, const float* __restrict__ Wd2,
                        const float* __restrict__ U1,  const float* __restrict__ U2,
                        const float* __restrict__ ba1, const float* __restrict__ bu1,
                        const float* __restrict__ ba2, const float* __restrict__ bu2,
                        const float* __restrict__ Wb,
                        unsigned short* __restrict__ embT, unsigned short* __restrict__ Wg,
                        unsigned short* __restrict__ Wd,   unsigned short* __restrict__ Ub,
                        unsigned short* __restrict__ Wbb,  float* __restrict__ bg,
                        unsigned int* __restrict__ cnt) {
    int tid = blockIdx.x * blockDim.x + threadIdx.x;
    int np = gridDim.x * blockDim.x;
    for (int i = tid; i < 256 * VP_; i += np) {
        int n = i / VP_, k = i - n * VP_;
        embT[i] = (k < V_) ? f2bf(emb[k * H_ + n]) : (unsigned short)0;
    }
    for (int i = tid; i < G4_ * H_; i += np) {
        Wg[i] = f2bf(Wa1[i]); Wg[G4_ * H_ + i] = f2bf(Wa2[i]);
        Ub[i] = f2bf(U1[i]);  Ub[G4_ * H_ + i] = f2bf(U2[i]);
    }
    for (int i = tid; i < H_ * H_; i += np) {
        Wd[i] = f2bf(Wd1[i]); Wd[H_ * H_ + i] = f2bf(Wd2[i]); Wbb[i] = f2bf(Wb[i]);
    }
    for (int i = tid; i < G4_; i += np) {
        bg[i] = ba1[i] + bu1[i]; bg[G4_ + i] = ba2[i] + bu2[i];
    }
    for (int i = tid; i < 512; i += np) cnt[i] = 0;   // sync counters (re-zeroed every run)
}

// ---------------------------------------------------------------- K1: embedded = inputs @ emb
__global__ __launch_bounds__(512, 2) void k1_embed(const float* __restrict__ inputs,
                                                   const unsigned short* __restrict__ embT,
                                                   unsigned short* __restrict__ embB) {
    const int tid = threadIdx.x;
    const int w = tid >> 6, ln = tid & 63, q = ln >> 4, l16 = ln & 15;
    const int mt = w >> 2, ng = (w & 3) * 4;
    const int Rbase = blockIdx.x * 32 + mt * 16;
    const float* arow = inputs + (long)(Rbase + l16) * V_;

    f32x4 acc[4];
    #pragma unroll
    for (int i = 0; i < 4; ++i) acc[i] = (f32x4){0.f, 0.f, 0.f, 0.f};

    for (int kt = 0; kt < 44; ++kt) {
        int k0 = kt * 32 + q * 8;
        short8 af;
        if (kt == 43 && q == 3) {
            #pragma unroll
            for (int j = 0; j < 8; ++j) af[j] = 0;
        } else {
            f32x4 x0 = *(const f32x4*)(arow + k0);
            f32x4 x1 = *(const f32x4*)(arow + k0 + 4);
            #pragma unroll
            for (int j = 0; j < 4; ++j) { af[j] = (short)f2bf(x0[j]); af[4 + j] = (short)f2bf(x1[j]); }
        }
        #pragma unroll
        for (int i = 0; i < 4; ++i) {
            short8 bf = *(const short8*)(embT + (long)((ng + i) * 16 + l16) * VP_ + k0);
            acc[i] = __builtin_amdgcn_mfma_f32_16x16x32_bf16(af, bf, acc[i], 0, 0, 0);
        }
    }
    #pragma unroll
    for (int i = 0; i < 4; ++i) {
        int col = (ng + i) * 16 + l16;
        #pragma unroll
        for (int j = 0; j < 4; ++j) {
            int R = Rbase + 4 * q + j;
            embB[(long)R * H_ + col] = f2bf(acc[i][j]);
        }
    }
}

// ---------------------------------------------------------------- K2: P chunk = embedded @ [U1;U2]^T + bg
// P row-major fp32: P[l][localrow' = sc*64 + b][gatecol 0..1023]; chunk covers steps [t0,t0+64).
__global__ __launch_bounds__(512, 2) void k2_pre(const unsigned short* __restrict__ embB,
                                                 const unsigned short* __restrict__ Ub,
                                                 const float* __restrict__ bg,
                                                 float* __restrict__ P, int t0) {
    const int tid = threadIdx.x;
    const int w = tid >> 6, ln = tid & 63, q = ln >> 4, l16 = ln & 15;
    const int rbase = blockIdx.x * 32;  // local row' in chunk, 0..4095

    short8 af[2][8];
    #pragma unroll
    for (int mt = 0; mt < 2; ++mt)
        #pragma unroll
        for (int kt = 0; kt < 8; ++kt) {
            int rp = rbase + mt * 16 + l16;
            int rg = t0 * 64 + rp;
            int b = rg & 63, s = rg >> 6;
            af[mt][kt] = *(const short8*)(embB + ((long)b * S_ + s) * H_ + kt * 32 + q * 8);
        }

    for (int i = 0; i < 16; ++i) {
        int nt2 = w * 16 + i;          // global gate-col tile 0..127
        int l = nt2 >> 6;
        int gcol = (nt2 & 63) * 16 + l16;   // col within lstm, 0..1023
        float bias = bg[nt2 * 16 + l16];
        short8 bf[8];
        #pragma unroll
        for (int kt = 0; kt < 8; ++kt)
            bf[kt] = *(const short8*)(Ub + (long)(nt2 * 16 + l16) * H_ + kt * 32 + q * 8);
        #pragma unroll
        for (int mt = 0; mt < 2; ++mt) {
            f32x4 acc = (f32x4){bias, bias, bias, bias};
            #pragma unroll
            for (int kt = 0; kt < 8; ++kt)
                acc = __builtin_amdgcn_mfma_f32_16x16x32_bf16(af[mt][kt], bf[kt], acc, 0, 0, 0);
            int rp0 = rbase + mt * 16;
            // C layout: row = 4q+j (within tile), col = l16 -> explicit row-major store
            float* dst = P + ((long)l * (CH_ * 64) + rp0 + 4 * q) * G4_ + gcol;
            #pragma unroll
            for (int j = 0; j < 4; ++j) dst[(long)j * G4_] = acc[j];
        }
    }
}

// ---------------------------------------------------------------- K3: time-LSTM chunk (64 steps)
// REDESIGN (round 6): hidden-column partitioning with register-resident weights.
//   grid = 32 blocks = 2 lstm x 4 batch-tiles x 4 col-groups, 256 threads (4 waves).
//   Each wave owns 16 hidden cols: 4 gate W-tiles + 1 Wd-tile = 40 short8 = 160 VGPR,
//   loaded ONCE -> zero steady-state weight traffic (was ~520KB/CU/step from L2,
//   the structural bottleneck: 11.7us/step at 0.76% occupancy).
//   Per-step cross-block exchange of h (via out1/out2, sc1 write-through) and c
//   (parity-buffered cx, bf16 like the old c_lds) among the 4 col-blocks of each
//   (l,m) group: sc1 stores -> vmcnt(0) -> barrier -> atomicAdd(counter); peers
//   poll counter (relaxed agent load) then gather fragments with sc1 loads.
//   Numerics identical to previous version (h/c exchanged as bf16, c fp32 locally).
__global__ __launch_bounds__(256, 1) void k3_lstm(const float* __restrict__ ts,
                                                  const unsigned short* __restrict__ W, // Wg || Wd
                                                  const float* __restrict__ bd1,
                                                  const float* __restrict__ bd2,
                                                  const float* __restrict__ P,
                                                  unsigned short* __restrict__ out1,
                                                  unsigned short* __restrict__ out2,
                                                  float* __restrict__ cst,
                                                  unsigned short* __restrict__ cx,
                                                  unsigned int* __restrict__ cnt,
                                                  int t0) {
    __shared__ float ts_lds[16][CH_];

    const int tid = threadIdx.x;
    const int w = tid >> 6, ln = tid & 63, q = ln >> 4, l16 = ln & 15;
    const int bid = blockIdx.x;
    const int l = bid >> 4, m = (bid >> 2) & 3, cg = bid & 3;
    const int b0 = m * 16;
    const int hc0 = cg * 64 + w * 16;      // wave's hidden-col tile base
    const int mycol = hc0 + l16;
    const int cidx = (l * 4 + m) * 64;     // counter index, 256B-padded
    unsigned short* outp = l ? out2 : out1;
    const float bdv = (l ? bd2 : bd1)[mycol];

    for (int i = tid; i < 16 * CH_; i += 256) {
        int r = i >> 6, cc = i & (CH_ - 1);
        ts_lds[r][cc] = ts[(b0 + r) * S_ + t0 + cc];
    }

    // -------- register-resident weights (loaded once per launch) --------
    short8 wg[4][8];   // gate g, k-tile kt : B-frag rows = gate-col g*256+hc0+l16
    short8 wd[8];      // Wd rows = hidden col hc0+l16
    #pragma unroll
    for (int g = 0; g < 4; ++g)
        #pragma unroll
        for (int kt = 0; kt < 8; ++kt)
            wg[g][kt] = *(const short8*)(W + ((long)(l * G4_ + g * H_ + mycol)) * H_ + kt * 32 + q * 8);
    #pragma unroll
    for (int kt = 0; kt < 8; ++kt)
        wd[kt] = *(const short8*)(W + (long)2 * G4_ * H_ + ((long)(l * H_ + mycol)) * H_ + kt * 32 + q * 8);

    float cf[4];
    if (t0 == 0) {
        cf[0] = cf[1] = cf[2] = cf[3] = 0.f;
    } else {
        #pragma unroll
        for (int j = 0; j < 4; ++j)
            cf[j] = cst[(long)(l * 4 + m) * 4096 + (4 * q + j) * 256 + mycol];
    }
    __syncthreads();

    const float* Pbase = P + ((long)l * (CH_ * 64) + b0) * G4_;

    #pragma unroll 1
    for (int t = 0; t < CH_; ++t) {
        const int gt = t0 + t;

        // P(t) loads issued BEFORE the poll (peer-independent; latency hides under sync)
        float pv[4][4];
        #pragma unroll
        for (int g = 0; g < 4; ++g)
            #pragma unroll
            for (int j = 0; j < 4; ++j)
                pv[g][j] = Pbase[((long)t * 64 + 4 * q + j) * G4_ + g * H_ + mycol];
        asm volatile("" ::: "memory");   // keep P loads above the poll

        // wait for all 4 col-blocks of this (l,m) group to finish step gt-1
        if (tid == 0) {
            unsigned target = 4u * (unsigned)gt;
            while (__hip_atomic_load(&cnt[cidx], __ATOMIC_RELAXED, __HIP_MEMORY_SCOPE_AGENT) < target)
                __builtin_amdgcn_s_sleep(1);
        }
        __syncthreads();

        // gather h(gt-1) from out1/out2 and c(gt-1) from cx (device-coherent loads)
        short8 ha[8], ca[8];
        if (gt == 0) {
            #pragma unroll
            for (int kt = 0; kt < 8; ++kt) {
                #pragma unroll
                for (int j = 0; j < 8; ++j) { ha[kt][j] = 0; ca[kt][j] = 0; }
            }
        } else {
            const unsigned short* hrow = outp + ((long)(b0 + l16) * S_ + (gt - 1)) * H_ + q * 8;
            const unsigned short* crow = cx + ((long)(((gt - 1) & 1) * 8 + l * 4 + m)) * 4096 + l16 * 256 + q * 8;
            #pragma unroll
            for (int kt = 0; kt < 8; ++kt) ha[kt] = gload16_sc1(hrow + kt * 32);
            #pragma unroll
            for (int kt = 0; kt < 8; ++kt) ca[kt] = gload16_sc1(crow + kt * 32);
        }
        asm volatile("s_waitcnt vmcnt(0)" ::: "memory");
        __builtin_amdgcn_sched_barrier(0);

        // c_s1 pre-act: c @ W_d^T + b_d
        f32x4 dacc = (f32x4){bdv, bdv, bdv, bdv};
        #pragma unroll
        for (int kt = 0; kt < 8; ++kt)
            dacc = __builtin_amdgcn_mfma_f32_16x16x32_bf16(ca[kt], wd[kt], dacc, 0, 0, 0);

        // gates pre-act: h @ W_all^T + P
        f32x4 gacc[4];
        #pragma unroll
        for (int g = 0; g < 4; ++g) {
            gacc[g] = (f32x4){pv[g][0], pv[g][1], pv[g][2], pv[g][3]};
            #pragma unroll
            for (int kt = 0; kt < 8; ++kt)
                gacc[g] = __builtin_amdgcn_mfma_f32_16x16x32_bf16(ha[kt], wg[g][kt], gacc[g], 0, 0, 0);
        }

        // elementwise + device-scope stores (h -> out, c -> cx parity buffer)
        #pragma unroll
        for (int j = 0; j < 4; ++j) {
            int r = 4 * q + j;
            float tv = ts_lds[r][t];
            float cs1 = ftanh(dacc[j]);
            float cadj = cf[j] + cs1 * (tv - 1.0f);
            float fg = fsig(gacc[0][j]), ig = fsig(gacc[1][j]);
            float og = fsig(gacc[2][j]), ct = fsig(gacc[3][j]);
            float cn = fg * cadj + ig * ct;
            float hn = og * ftanh(cn);
            cf[j] = cn;
            gstore_short_sc1(outp + ((long)(b0 + r) * S_ + gt) * H_ + mycol, (unsigned)f2bf(hn));
            gstore_short_sc1(cx + ((long)((gt & 1) * 8 + l * 4 + m)) * 4096 + r * 256 + mycol, (unsigned)f2bf(cn));
        }

        asm volatile("s_waitcnt vmcnt(0)" ::: "memory");   // sc1 stores at coherent point
        __syncthreads();                                    // all 4 waves drained
        if (tid == 0) atomicAdd(&cnt[cidx], 1u);            // announce step gt done
    }

    // persist fp32 c for next chunk
    #pragma unroll
    for (int j = 0; j < 4; ++j)
        cst[(long)(l * 4 + m) * 4096 + (4 * q + j) * 256 + mycol] = cf[j];
}

// ---------------------------------------------------------------- K4a: scores + softmax -> alpha
__global__ __launch_bounds__(512) void k4a_alpha(const unsigned short* __restrict__ out1,
                                                 const float* __restrict__ wa,
                                                 float* __restrict__ alpha) {
    __shared__ float sc[512];
    __shared__ float red[512];
    const int b = blockIdx.x, tid = threadIdx.x;
    const int w = tid >> 6, ln = tid & 63;
    f32x4 wv = *(const f32x4*)(wa + ln * 4);
    for (int i = 0; i < 64; ++i) {
        int s = w * 64 + i;
        const unsigned short* row = out1 + ((long)b * S_ + s) * H_ + ln * 4;
        float d = bf2f(row[0]) * wv[0] + bf2f(row[1]) * wv[1] +
                  bf2f(row[2]) * wv[2] + bf2f(row[3]) * wv[3];
        #pragma unroll
        for (int off = 32; off; off >>= 1) d += __shfl_xor(d, off);
        if (ln == 0) sc[s] = d;
    }
    __syncthreads();
    float v = sc[tid];
    red[tid] = v;
    for (int st = 256; st; st >>= 1) {
        __syncthreads();
        if (tid < st) red[tid] = fmaxf(red[tid], red[tid + st]);
    }
    __syncthreads();
    float M = red[0];
    __syncthreads();
    float e = __builtin_amdgcn_exp2f((v - M) * 1.44269504f);
    red[tid] = e;
    for (int st = 256; st; st >>= 1) {
        __syncthreads();
        if (tid < st) red[tid] += red[tid + st];
    }
    __syncthreads();
    alpha[b * S_ + tid] = e * __builtin_amdgcn_rcpf(red[0]);
}

// ---------------------------------------------------------------- K4b: Beta=tanh(out2@Wb^T); ctx = sum_s emb*Beta*alpha
__global__ __launch_bounds__(512, 2) void k4b_ctx(const unsigned short* __restrict__ out2,
                                                  const unsigned short* __restrict__ Wbb,
                                                  const unsigned short* __restrict__ embB,
                                                  const float* __restrict__ alpha,
                                                  float* __restrict__ ctx) {
    __shared__ float cbuf[32][256];
    const int b = blockIdx.x, tid = threadIdx.x;
    const int w = tid >> 6, ln = tid & 63, q = ln >> 4, l16 = ln & 15;

    float cp[16];
    #pragma unroll
    for (int nt = 0; nt < 16; ++nt) cp[nt] = 0.f;

    for (int i = 0; i < 4; ++i) {
        int mt = w * 4 + i;
        short8 af[8];
        #pragma unroll
        for (int kt = 0; kt < 8; ++kt)
            af[kt] = *(const short8*)(out2 + ((long)b * S_ + mt * 16 + l16) * H_ + kt * 32 + q * 8);
        float al[4];
        #pragma unroll
        for (int j = 0; j < 4; ++j) al[j] = alpha[b * S_ + mt * 16 + 4 * q + j];
        for (int nt = 0; nt < 16; ++nt) {
            f32x4 acc = (f32x4){0.f, 0.f, 0.f, 0.f};
            #pragma unroll
            for (int kt = 0; kt < 8; ++kt) {
                short8 bf = *(const short8*)(Wbb + (long)(nt * 16 + l16) * H_ + kt * 32 + q * 8);
                acc = __builtin_amdgcn_mfma_f32_16x16x32_bf16(af[kt], bf, acc, 0, 0, 0);
            }
            #pragma unroll
            for (int j = 0; j < 4; ++j) {
                int s = mt * 16 + 4 * q + j;
                float beta = ftanh(acc[j]);
                float ev = bf2f(embB[((long)b * S_ + s) * H_ + nt * 16 + l16]);
                cp[nt] += beta * al[j] * ev;
            }
        }
    }
    #pragma unroll
    for (int nt = 0; nt < 16; ++nt) cbuf[w * 4 + q][nt * 16 + l16] = cp[nt];
    __syncthreads();
    if (tid < 256) {
        float sum = 0.f;
        for (int i = 0; i < 32; ++i) sum += cbuf[i][tid];
        ctx[b * H_ + tid] = sum;
    }
}

// ---------------------------------------------------------------- K4c: out = ctx @ W_out^T
__global__ void k4c_out(const float* __restrict__ ctx, const float* __restrict__ Wout,
                        float* __restrict__ out) {
    int b = blockIdx.x, n = threadIdx.x;
    const f32x4* cr = (const f32x4*)(ctx + b * H_);
    const f32x4* wr = (const f32x4*)(Wout + n * H_);
    float acc = 0.f;
    #pragma unroll 8
    for (int i = 0; i < 64; ++i) {
        f32x4 c = cr[i], ww = wr[i];
        acc += c[0] * ww[0] + c[1] * ww[1] + c[2] * ww[2] + c[3] * ww[3];
    }
    out[b * NC_ + n] = acc;
}

// ---------------------------------------------------------------- launch
extern "C" void kernel_launch(void* const* d_in, const int* in_sizes, int n_in,
                              void* d_out, int out_size, void* d_ws, size_t ws_size,
                              hipStream_t stream) {
    (void)in_sizes; (void)n_in; (void)out_size; (void)ws_size;
    const float* inputs = (const float*)d_in[0];
    const float* tsp    = (const float*)d_in[1];
    const float* emb    = (const float*)d_in[2];
    const float* Wa1 = (const float*)d_in[3];  const float* ba1 = (const float*)d_in[4];
    const float* U1  = (const float*)d_in[5];  const float* bu1 = (const float*)d_in[6];
    const float* Wd1 = (const float*)d_in[7];  const float* bd1 = (const float*)d_in[8];
    const float* Wa2 = (const float*)d_in[9];  const float* ba2 = (const float*)d_in[10];
    const float* U2  = (const float*)d_in[11]; const float* bu2 = (const float*)d_in[12];
    const float* Wd2 = (const float*)d_in[13]; const float* bd2 = (const float*)d_in[14];
    const float* wa  = (const float*)d_in[15];
    const float* Wb  = (const float*)d_in[16];
    const float* Wout = (const float*)d_in[17];
    float* out = (float*)d_out;

    // Workspace map (round-6: hst dropped — h persists via out1/out2; cx is the
    // bf16 c-exchange parity buffer; cnt holds 8 padded sync counters).
    char* ws = (char*)d_ws;
    unsigned short* embT = (unsigned short*)(ws + 0);            //    720,896
    unsigned short* Wg   = (unsigned short*)(ws + 720896);       //  1,048,576 (Wd must follow)
    unsigned short* Wd   = (unsigned short*)(ws + 1769472);      //    262,144
    unsigned short* Ub   = (unsigned short*)(ws + 2031616);      //  1,048,576
    unsigned short* Wbb  = (unsigned short*)(ws + 3080192);      //    131,072
    float*          bgp  = (float*)(ws + 3211264);               //      8,192
    unsigned short* embB = (unsigned short*)(ws + 3219456);      // 16,777,216
    float*          P    = (float*)(ws + 19996672);              // 33,554,432 (64-step chunk)
    unsigned short* out1 = (unsigned short*)(ws + 53551104);     // 16,777,216
    unsigned short* out2 = (unsigned short*)(ws + 70328320);     // 16,777,216
    unsigned short* cx   = (unsigned short*)(ws + 87105536);     //    131,072 ([2 parity][8 grp][16][256] bf16)
    float*          cst  = (float*)(ws + 87236608);              //    131,072
    float*          alp  = (float*)(ws + 87367680);              //    131,072
    float*          ctx  = (float*)(ws + 87498752);              //     65,536
    unsigned int*   cnt  = (unsigned int*)(ws + 87564288);       //      2,048
    // total: 87,566,336 bytes (~83.5 MiB)

    hipLaunchKernelGGL(k0_prep, dim3(256), dim3(256), 0, stream,
                       emb, Wa1, Wa2, Wd1, Wd2, U1, U2, ba1, bu1, ba2, bu2, Wb,
                       embT, Wg, Wd, Ub, Wbb, bgp, cnt);
    hipLaunchKernelGGL(k1_embed, dim3(1024), dim3(512), 0, stream, inputs, embT, embB);
    for (int c = 0; c < 8; ++c) {
        hipLaunchKernelGGL(k2_pre, dim3(128), dim3(512), 0, stream, embB, Ub, bgp, P, c * CH_);
        hipLaunchKernelGGL(k3_lstm, dim3(32), dim3(256), 0, stream, tsp, Wg, bd1, bd2, P,
                           out1, out2, cst, cx, cnt, c * CH_);
    }
    hipLaunchKernelGGL(k4a_alpha, dim3(64), dim3(512), 0, stream, out1, wa, alp);
    hipLaunchKernelGGL(k4b_ctx, dim3(64), dim3(512), 0, stream, out2, Wbb, embB, alp, ctx);
    hipLaunchKernelGGL(k4c_out, dim3(64), dim3(128), 0, stream, ctx, Wout, out);
}

// Round 2
// 2982.718 us; speedup vs baseline: 2.2989x; 1.0151x over previous
//
#include <hip/hip_runtime.h>

typedef __attribute__((ext_vector_type(8))) short short8;
typedef __attribute__((ext_vector_type(4))) float f32x4;

#define B_   64
#define S_   512
#define V_   1400
#define VP_  1408
#define H_   256
#define G4_  1024
#define NC_  128
#define CH_  64    // time-chunk length (8 chunks of 64 steps)

__device__ __forceinline__ unsigned short f2bf(float f) {
    unsigned u = __builtin_bit_cast(unsigned, f);
    u += 0x7FFFu + ((u >> 16) & 1u);
    return (unsigned short)(u >> 16);
}
__device__ __forceinline__ float bf2f(unsigned short h) {
    unsigned u = ((unsigned)h) << 16;
    return __builtin_bit_cast(float, u);
}
__device__ __forceinline__ float fsig(float x) {
    x = fminf(fmaxf(x, -40.f), 40.f);
    float e = __builtin_amdgcn_exp2f(x * -1.44269504f);
    return __builtin_amdgcn_rcpf(1.0f + e);
}
__device__ __forceinline__ float ftanh(float x) {
    x = fminf(fmaxf(x, -40.f), 40.f);
    float e = __builtin_amdgcn_exp2f(x * 2.88539008f);
    return 1.0f - 2.0f * __builtin_amdgcn_rcpf(e + 1.0f);
}

// device-scope (coherent-point) 16B load: bypasses non-coherent L1/L2 so
// cross-XCD peer data is seen without cache invalidates. NOTE: no "memory"
// clobber — volatile asm order among volatile asms is preserved, and the
// explicit waitcnt fences carry the ordering we need.
__device__ __forceinline__ short8 gload16_sc1(const unsigned short* p) {
    short8 r;
    asm volatile("global_load_dwordx4 %0, %1, off sc1"
                 : "=v"(r) : "v"((unsigned long long)p));
    return r;
}
// device-scope write-through 2B store (peer-visible after vmcnt drain).
// No "memory" clobber (round-7): clobbers forced the allocator to treat the
// pre-loaded weight fragments as reloadable -> 160KB/CU/step L2 re-fetch.
__device__ __forceinline__ void gstore_short_sc1(unsigned short* p, unsigned v) {
    asm volatile("global_store_short %0, %1, off sc1"
                 :: "v"((unsigned long long)p), "v"(v));
}

// ---------------------------------------------------------------- K0: prep
__global__ void k0_prep(const float* __restrict__ emb,
                        const float* __restrict__ Wa1, const float* __restrict__ Wa2,
                        const float* __restrict__ Wd1, const float* __restrict__ Wd2,
                        const float* __restrict__ U1,  const float* __restrict__ U2,
                        const float* __restrict__ ba1, const float* __restrict__ bu1,
                        const float* __restrict__ ba2, const float* __restrict__ bu2,
                        const float* __restrict__ Wb,
                        unsigned short* __restrict__ embT, unsigned short* __restrict__ Wg,
                        unsigned short* __restrict__ Wd,   unsigned short* __restrict__ Ub,
                        unsigned short* __restrict__ Wbb,  float* __restrict__ bg,
                        unsigned int* __restrict__ cnt) {
    int tid = blockIdx.x * blockDim.x + threadIdx.x;
    int np = gridDim.x * blockDim.x;
    for (int i = tid; i < 256 * VP_; i += np) {
        int n = i / VP_, k = i - n * VP_;
        embT[i] = (k < V_) ? f2bf(emb[k * H_ + n]) : (unsigned short)0;
    }
    for (int i = tid; i < G4_ * H_; i += np) {
        Wg[i] = f2bf(Wa1[i]); Wg[G4_ * H_ + i] = f2bf(Wa2[i]);
        Ub[i] = f2bf(U1[i]);  Ub[G4_ * H_ + i] = f2bf(U2[i]);
    }
    for (int i = tid; i < H_ * H_; i += np) {
        Wd[i] = f2bf(Wd1[i]); Wd[H_ * H_ + i] = f2bf(Wd2[i]); Wbb[i] = f2bf(Wb[i]);
    }
    for (int i = tid; i < G4_; i += np) {
        bg[i] = ba1[i] + bu1[i]; bg[G4_ + i] = ba2[i] + bu2[i];
    }
    for (int i = tid; i < 512; i += np) cnt[i] = 0;   // sync counters (re-zeroed every run)
}

// ---------------------------------------------------------------- K1: embedded = inputs @ emb
__global__ __launch_bounds__(512, 2) void k1_embed(const float* __restrict__ inputs,
                                                   const unsigned short* __restrict__ embT,
                                                   unsigned short* __restrict__ embB) {
    const int tid = threadIdx.x;
    const int w = tid >> 6, ln = tid & 63, q = ln >> 4, l16 = ln & 15;
    const int mt = w >> 2, ng = (w & 3) * 4;
    const int Rbase = blockIdx.x * 32 + mt * 16;
    const float* arow = inputs + (long)(Rbase + l16) * V_;

    f32x4 acc[4];
    #pragma unroll
    for (int i = 0; i < 4; ++i) acc[i] = (f32x4){0.f, 0.f, 0.f, 0.f};

    for (int kt = 0; kt < 44; ++kt) {
        int k0 = kt * 32 + q * 8;
        short8 af;
        if (kt == 43 && q == 3) {
            #pragma unroll
            for (int j = 0; j < 8; ++j) af[j] = 0;
        } else {
            f32x4 x0 = *(const f32x4*)(arow + k0);
            f32x4 x1 = *(const f32x4*)(arow + k0 + 4);
            #pragma unroll
            for (int j = 0; j < 4; ++j) { af[j] = (short)f2bf(x0[j]); af[4 + j] = (short)f2bf(x1[j]); }
        }
        #pragma unroll
        for (int i = 0; i < 4; ++i) {
            short8 bf = *(const short8*)(embT + (long)((ng + i) * 16 + l16) * VP_ + k0);
            acc[i] = __builtin_amdgcn_mfma_f32_16x16x32_bf16(af, bf, acc[i], 0, 0, 0);
        }
    }
    #pragma unroll
    for (int i = 0; i < 4; ++i) {
        int col = (ng + i) * 16 + l16;
        #pragma unroll
        for (int j = 0; j < 4; ++j) {
            int R = Rbase + 4 * q + j;
            embB[(long)R * H_ + col] = f2bf(acc[i][j]);
        }
    }
}

// ---------------------------------------------------------------- K2: P chunk = embedded @ [U1;U2]^T + bg
// P row-major fp32: P[l][localrow' = sc*64 + b][gatecol 0..1023]; chunk covers steps [t0,t0+64).
__global__ __launch_bounds__(512, 2) void k2_pre(const unsigned short* __restrict__ embB,
                                                 const unsigned short* __restrict__ Ub,
                                                 const float* __restrict__ bg,
                                                 float* __restrict__ P, int t0) {
    const int tid = threadIdx.x;
    const int w = tid >> 6, ln = tid & 63, q = ln >> 4, l16 = ln & 15;
    const int rbase = blockIdx.x * 32;  // local row' in chunk, 0..4095

    short8 af[2][8];
    #pragma unroll
    for (int mt = 0; mt < 2; ++mt)
        #pragma unroll
        for (int kt = 0; kt < 8; ++kt) {
            int rp = rbase + mt * 16 + l16;
            int rg = t0 * 64 + rp;
            int b = rg & 63, s = rg >> 6;
            af[mt][kt] = *(const short8*)(embB + ((long)b * S_ + s) * H_ + kt * 32 + q * 8);
        }

    for (int i = 0; i < 16; ++i) {
        int nt2 = w * 16 + i;          // global gate-col tile 0..127
        int l = nt2 >> 6;
        int gcol = (nt2 & 63) * 16 + l16;   // col within lstm, 0..1023
        float bias = bg[nt2 * 16 + l16];
        short8 bf[8];
        #pragma unroll
        for (int kt = 0; kt < 8; ++kt)
            bf[kt] = *(const short8*)(Ub + (long)(nt2 * 16 + l16) * H_ + kt * 32 + q * 8);
        #pragma unroll
        for (int mt = 0; mt < 2; ++mt) {
            f32x4 acc = (f32x4){bias, bias, bias, bias};
            #pragma unroll
            for (int kt = 0; kt < 8; ++kt)
                acc = __builtin_amdgcn_mfma_f32_16x16x32_bf16(af[mt][kt], bf[kt], acc, 0, 0, 0);
            int rp0 = rbase + mt * 16;
            // C layout: row = 4q+j (within tile), col = l16 -> explicit row-major store
            float* dst = P + ((long)l * (CH_ * 64) + rp0 + 4 * q) * G4_ + gcol;
            #pragma unroll
            for (int j = 0; j < 4; ++j) dst[(long)j * G4_] = acc[j];
        }
    }
}

// ---------------------------------------------------------------- K3: time-LSTM chunk (64 steps)
// Round-7 refinements on the hidden-column-partitioned design:
//  (1) weight fragments PINNED in registers via empty asm "+v" after the
//      one-time load — forbids remat-by-reload (VGPR 144 proved the allocator
//      was re-streaming 160KB/CU/step of weights from L2, ~2900 cy/step).
//  (2) partial-wait gather: ca issued first, dacc MFMAs run behind vmcnt(8),
//      vmcnt(0) only before gacc; sched_barrier(0) after each wait.
//  (3) all-lanes counter poll (merged same-address loads) -> post-poll
//      __syncthreads removed. Pre-add barrier retained, so the counter still
//      certifies whole-block drain and the parity-2 c-exchange stays safe.
__global__ __launch_bounds__(256, 1) void k3_lstm(const float* __restrict__ ts,
                                                  const unsigned short* __restrict__ W, // Wg || Wd
                                                  const float* __restrict__ bd1,
                                                  const float* __restrict__ bd2,
                                                  const float* __restrict__ P,
                                                  unsigned short* __restrict__ out1,
                                                  unsigned short* __restrict__ out2,
                                                  float* __restrict__ cst,
                                                  unsigned short* __restrict__ cx,
                                                  unsigned int* __restrict__ cnt,
                                                  int t0) {
    __shared__ float ts_lds[16][CH_];

    const int tid = threadIdx.x;
    const int w = tid >> 6, ln = tid & 63, q = ln >> 4, l16 = ln & 15;
    const int bid = blockIdx.x;
    const int l = bid >> 4, m = (bid >> 2) & 3, cg = bid & 3;
    const int b0 = m * 16;
    const int hc0 = cg * 64 + w * 16;      // wave's hidden-col tile base
    const int mycol = hc0 + l16;
    const int cidx = (l * 4 + m) * 64;     // counter index, 256B-padded
    unsigned short* outp = l ? out2 : out1;
    const float bdv = (l ? bd2 : bd1)[mycol];

    for (int i = tid; i < 16 * CH_; i += 256) {
        int r = i >> 6, cc = i & (CH_ - 1);
        ts_lds[r][cc] = ts[(b0 + r) * S_ + t0 + cc];
    }

    // -------- register-resident weights (loaded once per launch) --------
    short8 wg[4][8];   // gate g, k-tile kt : B-frag rows = gate-col g*256+hc0+l16
    short8 wd[8];      // Wd rows = hidden col hc0+l16
    #pragma unroll
    for (int g = 0; g < 4; ++g)
        #pragma unroll
        for (int kt = 0; kt < 8; ++kt)
            wg[g][kt] = *(const short8*)(W + ((long)(l * G4_ + g * H_ + mycol)) * H_ + kt * 32 + q * 8);
    #pragma unroll
    for (int kt = 0; kt < 8; ++kt)
        wd[kt] = *(const short8*)(W + (long)2 * G4_ * H_ + ((long)(l * H_ + mycol)) * H_ + kt * 32 + q * 8);

    // PIN: make the weight values' origin opaque so no pass can turn them back
    // into per-iteration loads (the round-6 kernel reloaded them every step).
    #pragma unroll
    for (int g = 0; g < 4; ++g)
        #pragma unroll
        for (int kt = 0; kt < 8; ++kt)
            asm volatile("" : "+v"(wg[g][kt]));
    #pragma unroll
    for (int kt = 0; kt < 8; ++kt)
        asm volatile("" : "+v"(wd[kt]));

    float cf[4];
    if (t0 == 0) {
        cf[0] = cf[1] = cf[2] = cf[3] = 0.f;
    } else {
        #pragma unroll
        for (int j = 0; j < 4; ++j)
            cf[j] = cst[(long)(l * 4 + m) * 4096 + (4 * q + j) * 256 + mycol];
    }
    __syncthreads();

    const float* Pbase = P + ((long)l * (CH_ * 64) + b0) * G4_;

    #pragma unroll 1
    for (int t = 0; t < CH_; ++t) {
        const int gt = t0 + t;

        // P(t) loads issued BEFORE the poll (peer-independent; latency hides under sync)
        float pv[4][4];
        #pragma unroll
        for (int g = 0; g < 4; ++g)
            #pragma unroll
            for (int j = 0; j < 4; ++j)
                pv[g][j] = Pbase[((long)t * 64 + 4 * q + j) * G4_ + g * H_ + mycol];
        asm volatile("" ::: "memory");   // keep P loads above the poll

        // wait for all 4 col-blocks of this (l,m) group to finish step gt-1.
        // All lanes poll (same-address loads merge); no barrier needed after —
        // each wave's gathers are covered by the group counter independently.
        {
            unsigned target = 4u * (unsigned)gt;
            while (__hip_atomic_load(&cnt[cidx], __ATOMIC_RELAXED, __HIP_MEMORY_SCOPE_AGENT) < target)
                __builtin_amdgcn_s_sleep(1);
        }

        // gather c(gt-1) then h(gt-1) (device-coherent loads; ca first so dacc
        // can start behind a partial wait while ha completes)
        short8 ha[8], ca[8];
        if (gt == 0) {
            #pragma unroll
            for (int kt = 0; kt < 8; ++kt) {
                #pragma unroll
                for (int j = 0; j < 8; ++j) { ha[kt][j] = 0; ca[kt][j] = 0; }
            }
        } else {
            const unsigned short* crow = cx + ((long)(((gt - 1) & 1) * 8 + l * 4 + m)) * 4096 + l16 * 256 + q * 8;
            const unsigned short* hrow = outp + ((long)(b0 + l16) * S_ + (gt - 1)) * H_ + q * 8;
            #pragma unroll
            for (int kt = 0; kt < 8; ++kt) ca[kt] = gload16_sc1(crow + kt * 32);
            #pragma unroll
            for (int kt = 0; kt < 8; ++kt) ha[kt] = gload16_sc1(hrow + kt * 32);
        }
        asm volatile("s_waitcnt vmcnt(8)" ::: "memory");   // pv + ca complete
        __builtin_amdgcn_sched_barrier(0);

        // c_s1 pre-act: c @ W_d^T + b_d (runs while ha lands)
        f32x4 dacc = (f32x4){bdv, bdv, bdv, bdv};
        #pragma unroll
        for (int kt = 0; kt < 8; ++kt)
            dacc = __builtin_amdgcn_mfma_f32_16x16x32_bf16(ca[kt], wd[kt], dacc, 0, 0, 0);

        asm volatile("s_waitcnt vmcnt(0)" ::: "memory");   // ha complete
        __builtin_amdgcn_sched_barrier(0);

        // gates pre-act: h @ W_all^T + P
        f32x4 gacc[4];
        #pragma unroll
        for (int g = 0; g < 4; ++g) {
            gacc[g] = (f32x4){pv[g][0], pv[g][1], pv[g][2], pv[g][3]};
            #pragma unroll
            for (int kt = 0; kt < 8; ++kt)
                gacc[g] = __builtin_amdgcn_mfma_f32_16x16x32_bf16(ha[kt], wg[g][kt], gacc[g], 0, 0, 0);
        }

        // elementwise + device-scope stores (h -> out, c -> cx parity buffer)
        #pragma unroll
        for (int j = 0; j < 4; ++j) {
            int r = 4 * q + j;
            float tv = ts_lds[r][t];
            float cs1 = ftanh(dacc[j]);
            float cadj = cf[j] + cs1 * (tv - 1.0f);
            float fg = fsig(gacc[0][j]), ig = fsig(gacc[1][j]);
            float og = fsig(gacc[2][j]), ct = fsig(gacc[3][j]);
            float cn = fg * cadj + ig * ct;
            float hn = og * ftanh(cn);
            cf[j] = cn;
            gstore_short_sc1(outp + ((long)(b0 + r) * S_ + gt) * H_ + mycol, (unsigned)f2bf(hn));
            gstore_short_sc1(cx + ((long)((gt & 1) * 8 + l * 4 + m)) * 4096 + r * 256 + mycol, (unsigned)f2bf(cn));
        }

        asm volatile("s_waitcnt vmcnt(0)" ::: "memory");   // sc1 stores at coherent point
        __syncthreads();                                    // all 4 waves drained
        if (tid == 0) atomicAdd(&cnt[cidx], 1u);            // announce step gt done
    }

    // persist fp32 c for next chunk
    #pragma unroll
    for (int j = 0; j < 4; ++j)
        cst[(long)(l * 4 + m) * 4096 + (4 * q + j) * 256 + mycol] = cf[j];
}

// ---------------------------------------------------------------- K4a: scores + softmax -> alpha
__global__ __launch_bounds__(512) void k4a_alpha(const unsigned short* __restrict__ out1,
                                                 const float* __restrict__ wa,
                                                 float* __restrict__ alpha) {
    __shared__ float sc[512];
    __shared__ float red[512];
    const int b = blockIdx.x, tid = threadIdx.x;
    const int w = tid >> 6, ln = tid & 63;
    f32x4 wv = *(const f32x4*)(wa + ln * 4);
    for (int i = 0; i < 64; ++i) {
        int s = w * 64 + i;
        const unsigned short* row = out1 + ((long)b * S_ + s) * H_ + ln * 4;
        float d = bf2f(row[0]) * wv[0] + bf2f(row[1]) * wv[1] +
                  bf2f(row[2]) * wv[2] + bf2f(row[3]) * wv[3];
        #pragma unroll
        for (int off = 32; off; off >>= 1) d += __shfl_xor(d, off);
        if (ln == 0) sc[s] = d;
    }
    __syncthreads();
    float v = sc[tid];
    red[tid] = v;
    for (int st = 256; st; st >>= 1) {
        __syncthreads();
        if (tid < st) red[tid] = fmaxf(red[tid], red[tid + st]);
    }
    __syncthreads();
    float M = red[0];
    __syncthreads();
    float e = __builtin_amdgcn_exp2f((v - M) * 1.44269504f);
    red[tid] = e;
    for (int st = 256; st; st >>= 1) {
        __syncthreads();
        if (tid < st) red[tid] += red[tid + st];
    }
    __syncthreads();
    alpha[b * S_ + tid] = e * __builtin_amdgcn_rcpf(red[0]);
}

// ---------------------------------------------------------------- K4b: Beta=tanh(out2@Wb^T); ctx = sum_s emb*Beta*alpha
__global__ __launch_bounds__(512, 2) void k4b_ctx(const unsigned short* __restrict__ out2,
                                                  const unsigned short* __restrict__ Wbb,
                                                  const unsigned short* __restrict__ embB,
                                                  const float* __restrict__ alpha,
                                                  float* __restrict__ ctx) {
    __shared__ float cbuf[32][256];
    const int b = blockIdx.x, tid = threadIdx.x;
    const int w = tid >> 6, ln = tid & 63, q = ln >> 4, l16 = ln & 15;

    float cp[16];
    #pragma unroll
    for (int nt = 0; nt < 16; ++nt) cp[nt] = 0.f;

    for (int i = 0; i < 4; ++i) {
        int mt = w * 4 + i;
        short8 af[8];
        #pragma unroll
        for (int kt = 0; kt < 8; ++kt)
            af[kt] = *(const short8*)(out2 + ((long)b * S_ + mt * 16 + l16) * H_ + kt * 32 + q * 8);
        float al[4];
        #pragma unroll
        for (int j = 0; j < 4; ++j) al[j] = alpha[b * S_ + mt * 16 + 4 * q + j];
        for (int nt = 0; nt < 16; ++nt) {
            f32x4 acc = (f32x4){0.f, 0.f, 0.f, 0.f};
            #pragma unroll
            for (int kt = 0; kt < 8; ++kt) {
                short8 bf = *(const short8*)(Wbb + (long)(nt * 16 + l16) * H_ + kt * 32 + q * 8);
                acc = __builtin_amdgcn_mfma_f32_16x16x32_bf16(af[kt], bf, acc, 0, 0, 0);
            }
            #pragma unroll
            for (int j = 0; j < 4; ++j) {
                int s = mt * 16 + 4 * q + j;
                float beta = ftanh(acc[j]);
                float ev = bf2f(embB[((long)b * S_ + s) * H_ + nt * 16 + l16]);
                cp[nt] += beta * al[j] * ev;
            }
        }
    }
    #pragma unroll
    for (int nt = 0; nt < 16; ++nt) cbuf[w * 4 + q][nt * 16 + l16] = cp[nt];
    __syncthreads();
    if (tid < 256) {
        float sum = 0.f;
        for (int i = 0; i < 32; ++i) sum += cbuf[i][tid];
        ctx[b * H_ + tid] = sum;
    }
}

// ---------------------------------------------------------------- K4c: out = ctx @ W_out^T
__global__ void k4c_out(const float* __restrict__ ctx, const float* __restrict__ Wout,
                        float* __restrict__ out) {
    int b = blockIdx.x, n = threadIdx.x;
    const f32x4* cr = (const f32x4*)(ctx + b * H_);
    const f32x4* wr = (const f32x4*)(Wout + n * H_);
    float acc = 0.f;
    #pragma unroll 8
    for (int i = 0; i < 64; ++i) {
        f32x4 c = cr[i], ww = wr[i];
        acc += c[0] * ww[0] + c[1] * ww[1] + c[2] * ww[2] + c[3] * ww[3];
    }
    out[b * NC_ + n] = acc;
}

// ---------------------------------------------------------------- launch
extern "C" void kernel_launch(void* const* d_in, const int* in_sizes, int n_in,
                              void* d_out, int out_size, void* d_ws, size_t ws_size,
                              hipStream_t stream) {
    (void)in_sizes; (void)n_in; (void)out_size; (void)ws_size;
    const float* inputs = (const float*)d_in[0];
    const float* tsp    = (const float*)d_in[1];
    const float* emb    = (const float*)d_in[2];
    const float* Wa1 = (const float*)d_in[3];  const float* ba1 = (const float*)d_in[4];
    const float* U1  = (const float*)d_in[5];  const float* bu1 = (const float*)d_in[6];
    const float* Wd1 = (const float*)d_in[7];  const float* bd1 = (const float*)d_in[8];
    const float* Wa2 = (const float*)d_in[9];  const float* ba2 = (const float*)d_in[10];
    const float* U2  = (const float*)d_in[11]; const float* bu2 = (const float*)d_in[12];
    const float* Wd2 = (const float*)d_in[13]; const float* bd2 = (const float*)d_in[14];
    const float* wa  = (const float*)d_in[15];
    const float* Wb  = (const float*)d_in[16];
    const float* Wout = (const float*)d_in[17];
    float* out = (float*)d_out;

    // Workspace map (round-6: hst dropped — h persists via out1/out2; cx is the
    // bf16 c-exchange parity buffer; cnt holds 8 padded sync counters).
    char* ws = (char*)d_ws;
    unsigned short* embT = (unsigned short*)(ws + 0);            //    720,896
    unsigned short* Wg   = (unsigned short*)(ws + 720896);       //  1,048,576 (Wd must follow)
    unsigned short* Wd   = (unsigned short*)(ws + 1769472);      //    262,144
    unsigned short* Ub   = (unsigned short*)(ws + 2031616);      //  1,048,576
    unsigned short* Wbb  = (unsigned short*)(ws + 3080192);      //    131,072
    float*          bgp  = (float*)(ws + 3211264);               //      8,192
    unsigned short* embB = (unsigned short*)(ws + 3219456);      // 16,777,216
    float*          P    = (float*)(ws + 19996672);              // 33,554,432 (64-step chunk)
    unsigned short* out1 = (unsigned short*)(ws + 53551104);     // 16,777,216
    unsigned short* out2 = (unsigned short*)(ws + 70328320);     // 16,777,216
    unsigned short* cx   = (unsigned short*)(ws + 87105536);     //    131,072 ([2 parity][8 grp][16][256] bf16)
    float*          cst  = (float*)(ws + 87236608);              //    131,072
    float*          alp  = (float*)(ws + 87367680);              //    131,072
    float*          ctx  = (float*)(ws + 87498752);              //     65,536
    unsigned int*   cnt  = (unsigned int*)(ws + 87564288);       //      2,048
    // total: 87,566,336 bytes (~83.5 MiB)

    hipLaunchKernelGGL(k0_prep, dim3(256), dim3(256), 0, stream,
                       emb, Wa1, Wa2, Wd1, Wd2, U1, U2, ba1, bu1, ba2, bu2, Wb,
                       embT, Wg, Wd, Ub, Wbb, bgp, cnt);
    hipLaunchKernelGGL(k1_embed, dim3(1024), dim3(512), 0, stream, inputs, embT, embB);
    for (int c = 0; c < 8; ++c) {
        hipLaunchKernelGGL(k2_pre, dim3(128), dim3(512), 0, stream, embB, Ub, bgp, P, c * CH_);
        hipLaunchKernelGGL(k3_lstm, dim3(32), dim3(256), 0, stream, tsp, Wg, bd1, bd2, P,
                           out1, out2, cst, cx, cnt, c * CH_);
    }
    hipLaunchKernelGGL(k4a_alpha, dim3(64), dim3(512), 0, stream, out1, wa, alp);
    hipLaunchKernelGGL(k4b_ctx, dim3(64), dim3(512), 0, stream, out2, Wbb, embB, alp, ctx);
    hipLaunchKernelGGL(k4c_out, dim3(64), dim3(128), 0, stream, ctx, Wout, out);
}